// Round 4
// baseline (251.828 us; speedup 1.0000x reference)
//
#include <hip/hip_runtime.h>

// Problem constants (B=8192, S=32, N=128, K=64, M=3)
#define BATCH 8192
#define NBLK  512             // 4 waves/block, 4 consecutive batches per wave
#define EPSF  1e-9f
#define C_LD  36              // |C| LDS tile leading dim (measured 0 conflicts)
#define C_OFF 3072            // P ring: 3 slots x 1024 floats (4KB chunks)
#define WLDS  (C_OFF + 32 * C_LD)   // 4224 floats/wave = 16.9KB; x4 waves = 67.6KB

typedef float floatx16 __attribute__((ext_vector_type(16)));
typedef short shortx8  __attribute__((ext_vector_type(8)));
typedef __attribute__((address_space(1))) const void g_void;
typedef __attribute__((address_space(3))) void lds_void;

// insert v into descending top-4
__device__ __forceinline__ void ins4(float v, float& t0, float& t1, float& t2, float& t3) {
    float m;
    m = fminf(t0, v); t0 = fmaxf(t0, v); v = m;
    m = fminf(t1, v); t1 = fmaxf(t1, v); v = m;
    m = fminf(t2, v); t2 = fmaxf(t2, v); v = m;
    t3 = fmaxf(t3, v);
}

// merge a second descending top-4 (b0..b3) into t0..t3 (bitonic)
__device__ __forceinline__ void merge4(float& t0, float& t1, float& t2, float& t3,
                                       float b0, float b1, float b2, float b3) {
    float c0 = fmaxf(t0, b3);
    float c1 = fmaxf(t1, b2);
    float c2 = fmaxf(t2, b1);
    float c3 = fmaxf(t3, b0);
    float d0 = fmaxf(c0, c2), d2 = fminf(c0, c2);
    float d1 = fmaxf(c1, c3), d3 = fminf(c1, c3);
    t0 = fmaxf(d0, d1); t1 = fminf(d0, d1);
    t2 = fmaxf(d2, d3); t3 = fminf(d2, d3);
}

// R3 (resubmit; prior round was an infra failure, not a kernel failure):
// cross-batch software pipeline to fix the burst-drain memory duty cycle.
// Each wave handles 4 consecutive batches. P streams through a 3-slot LDS
// ring (4KB chunks, 16 rows each, chunk (it,k) -> slot (it+k)%3); x and y
// for batch it+1 are prefetched during batch it's MFMA phases. The DMA queue
// never drains: counted vmcnt waits keep 1-3 chunks + the x-burst in flight
// at all times.
//
// vmcnt bookkeeping (per batch it, steady state; each STAGE = 4 vmem insts):
//   enter batch: [c2(it)] maybe in flight; compiler's xs-use wait drains all
//     ops OLDER than xs(it) (= c0(it), c1(it)), leaves c2(it).
//   ks0: read slot sl0 (c0, drained); STAGE c3(it)     -> [c2?,c3]
//   ks1: read slot sl1 (c1, drained); STAGE c0(it+1)   -> [c2?,c3,c0']
//   ks2: wait vmcnt(8)  => c2 drained, keep [c3,c0'];
//        read sl2; STAGE c1'; issue xs(it+1)           -> [c3,c0',c1',X]=20
//   ks3: wait vmcnt(16) => c3 drained, keep [c0',c1',X]=16;
//        read sl0; STAGE c2(it+1)                      -> [c0',c1',X,c2']=20
//   (it==3: no next-batch issues; waits become vmcnt(4) / vmcnt(0).)
// Slot overwrite safety: each STAGE targets the slot whose reads completed
// in the immediately preceding KS (the 6 MFMAs consuming those ds_reads are
// issued before the STAGE; compiler lgkmcnt waits pin read completion).
// s_waitcnt never deadlocks (waits for counter <= N), so the counted-wait
// pipeline cannot hang.
__global__ __launch_bounds__(256, 2) void avl_main(
    const float* __restrict__ y_pred,
    const float* __restrict__ y_true,
    const float* __restrict__ P,   // [B][64][64]
    const float* __restrict__ X,   // [B][32][64]
    float* __restrict__ partial)   // [NBLK][2]: {violation_sum, logmse_sum}
{
    __shared__ float lds[4 * WLDS];   // 67584 B -> 2 blocks/CU
    __shared__ float red[8];

    const int tid  = threadIdx.x;
    const int wave = tid >> 6;
    const int lane = tid & 63;
    const int kg   = lane >> 5;   // K-half: this lane covers k = kg*8 + 16*ks + j
    const int m    = lane & 31;   // A row index == B col index == C col index

    // XCD-bijective swizzle: 512 wgs over 8 XCDs, 64 contiguous wgs per XCD
    const int bid = blockIdx.x;
    const int swz = (bid & 7) * 64 + (bid >> 3);
    const int b0  = swz * 16 + wave * 4;   // this wave: batches b0..b0+3

    float* ldsw = lds + wave * WLDS;

    // DMA one 16-row (4KB contiguous) P chunk of batch bb into ring slot
#define STAGE(slot, bb, kc) do {                                                   \
        const float* _s = P + (size_t)(bb) * 4096 + (kc) * 1024 + lane * 4;        \
        float* _d = ldsw + (slot) * 1024;                                          \
        __builtin_amdgcn_global_load_lds((g_void*)(_s),       (lds_void*)(_d),       16, 0, 0); \
        __builtin_amdgcn_global_load_lds((g_void*)(_s + 256), (lds_void*)(_d + 256), 16, 0, 0); \
        __builtin_amdgcn_global_load_lds((g_void*)(_s + 512), (lds_void*)(_d + 512), 16, 0, 0); \
        __builtin_amdgcn_global_load_lds((g_void*)(_s + 768), (lds_void*)(_d + 768), 16, 0, 0); \
    } while (0)

    // read chunk in `slot`, split to bf16 hi/lo, 6 MFMAs (both 32-col tiles)
#define KS(slot, ks_) do {                                                         \
        const float* pb_ = ldsw + (slot) * 1024;                                   \
        shortx8 bhi0, blo0, bhi1, blo1;                                            \
        _Pragma("unroll")                                                          \
        for (int j = 0; j < 8; ++j) {                                              \
            const int row_ = (kg * 8 + j) * 64 + m;                                \
            const float p0 = pb_[row_];                                            \
            const float p1 = pb_[row_ + 32];                                       \
            const unsigned u0 = __float_as_uint(p0);                               \
            bhi0[j] = (short)(u0 >> 16);                                           \
            blo0[j] = (short)(__float_as_uint(p0 - __uint_as_float(u0 & 0xFFFF0000u)) >> 16); \
            const unsigned u1 = __float_as_uint(p1);                               \
            bhi1[j] = (short)(u1 >> 16);                                           \
            blo1[j] = (short)(__float_as_uint(p1 - __uint_as_float(u1 & 0xFFFF0000u)) >> 16); \
        }                                                                          \
        acc[0] = __builtin_amdgcn_mfma_f32_32x32x16_bf16(alo[ks_], bhi0, acc[0], 0, 0, 0); \
        acc[0] = __builtin_amdgcn_mfma_f32_32x32x16_bf16(ahi[ks_], blo0, acc[0], 0, 0, 0); \
        acc[0] = __builtin_amdgcn_mfma_f32_32x32x16_bf16(ahi[ks_], bhi0, acc[0], 0, 0, 0); \
        acc[1] = __builtin_amdgcn_mfma_f32_32x32x16_bf16(alo[ks_], bhi1, acc[1], 0, 0, 0); \
        acc[1] = __builtin_amdgcn_mfma_f32_32x32x16_bf16(ahi[ks_], blo1, acc[1], 0, 0, 0); \
        acc[1] = __builtin_amdgcn_mfma_f32_32x32x16_bf16(ahi[ks_], bhi1, acc[1], 0, 0, 0); \
    } while (0)

    // y scalars for all 4 batches up-front (keeps C-phase free of vmem,
    // so no compiler vmcnt(0) drains mid-pipeline). b0 % 4 == 0 -> aligned.
    const float4 yp4 = *(const float4*)(y_pred + b0);
    const float4 yt4 = *(const float4*)(y_true + b0);

    // prologue: ring c0,c1,c2 of batch b0; x of b0
    STAGE(0, b0, 0);
    STAGE(1, b0, 1);
    STAGE(2, b0, 2);
    float4 xs[8];
    {
        const float* xg0 = X + (size_t)b0 * 2048 + m * 64 + kg * 8;
#pragma unroll
        for (int u = 0; u < 4; ++u) {
            xs[2 * u]     = *(const float4*)(xg0 + u * 16);
            xs[2 * u + 1] = *(const float4*)(xg0 + u * 16 + 4);
        }
    }

    float sV = 0.f, sL = 0.f;

    for (int it = 0; it < 4; ++it) {
        const int b  = b0 + it;
        const int nb = b + 1;
        const int sl0 = (it == 3) ? 0 : it;
        const int sl1 = (sl0 == 2) ? 0 : sl0 + 1;
        const int sl2 = (sl1 == 2) ? 0 : sl1 + 1;

        // ---- convert xs -> hi/lo A-frags; fold |x|; (compiler waits xs here,
        //      draining all vmem older than the xs loads) ----
        float t0 = -1.f, t1 = -1.f, t2 = -1.f, t3 = -1.f;
        shortx8 ahi[4], alo[4];
#pragma unroll
        for (int ks = 0; ks < 4; ++ks) {
            const float v[8] = { xs[2 * ks].x, xs[2 * ks].y, xs[2 * ks].z, xs[2 * ks].w,
                                 xs[2 * ks + 1].x, xs[2 * ks + 1].y, xs[2 * ks + 1].z, xs[2 * ks + 1].w };
#pragma unroll
            for (int i = 0; i < 8; ++i) {
                const float x = v[i];
                const unsigned bits = __float_as_uint(x);
                ahi[ks][i] = (short)(bits >> 16);
                const float hif = __uint_as_float(bits & 0xFFFF0000u);
                alo[ks][i] = (short)(__float_as_uint(x - hif) >> 16);
                ins4(fabsf(x), t0, t1, t2, t3);
            }
        }

        floatx16 acc[2];
#pragma unroll
        for (int t = 0; t < 2; ++t)
#pragma unroll
            for (int r = 0; r < 16; ++r) acc[t][r] = 0.f;

        // ---- ks0 (c0 already landed) ----
        KS(sl0, 0);
        STAGE(sl0, b, 3);                       // c3(it) into the slot ks0 just read
        // ---- ks1 ----
        KS(sl1, 1);
        if (it < 3) STAGE(sl1, nb, 0);          // c0(it+1)
        // ---- ks2 ----
        if (it < 3) asm volatile("s_waitcnt vmcnt(8)" ::: "memory");
        else        asm volatile("s_waitcnt vmcnt(4)" ::: "memory");
        __builtin_amdgcn_sched_barrier(0);
        KS(sl2, 2);
        if (it < 3) {
            STAGE(sl2, nb, 1);                  // c1(it+1)
            const float* xgn = X + (size_t)nb * 2048 + m * 64 + kg * 8;
#pragma unroll
            for (int u = 0; u < 4; ++u) {
                xs[2 * u]     = *(const float4*)(xgn + u * 16);
                xs[2 * u + 1] = *(const float4*)(xgn + u * 16 + 4);
            }
        }
        // ---- ks3 ----
        if (it < 3) asm volatile("s_waitcnt vmcnt(16)" ::: "memory");
        else        asm volatile("s_waitcnt vmcnt(0)"  ::: "memory");
        __builtin_amdgcn_sched_barrier(0);
        KS(sl0, 3);
        if (it < 3) STAGE(sl0, nb, 2);          // c2(it+1)

        // ---- C-phase: |C| -> per-wave LDS tile, row-major top-4 fold ----
        float* Cw = ldsw + C_OFF;
#pragma unroll
        for (int tile = 0; tile < 2; ++tile) {
#pragma unroll
            for (int reg = 0; reg < 16; ++reg) {
                const int row = (reg & 3) + 8 * (reg >> 2) + 4 * kg;
                Cw[row * C_LD + m] = fabsf(acc[tile][reg]);
            }
            const float* cr = Cw + m * C_LD + kg * 16;
#pragma unroll
            for (int t = 0; t < 4; ++t) {
                const float4 c = *(const float4*)(cr + 4 * t);
                ins4(c.x, t0, t1, t2, t3);
                ins4(c.y, t0, t1, t2, t3);
                ins4(c.z, t0, t1, t2, t3);
                ins4(c.w, t0, t1, t2, t3);
            }
        }

        // merge complementary half (lane L and L^32 cover disjoint sets)
        {
            const float m0 = __shfl_xor(t0, 32, 64);
            const float m1 = __shfl_xor(t1, 32, 64);
            const float m2 = __shfl_xor(t2, 32, 64);
            const float m3 = __shfl_xor(t3, 32, 64);
            merge4(t0, t1, t2, t3, m0, m1, m2, m3);
        }

        float h = t0 / (t3 + EPSF);
#pragma unroll
        for (int msk = 1; msk <= 16; msk <<= 1)
            h = fmaxf(h, __shfl_xor(h, msk, 64));

        const float ypc = (it == 0) ? yp4.x : (it == 1) ? yp4.y : (it == 2) ? yp4.z : yp4.w;
        const float ytc = (it == 0) ? yt4.x : (it == 1) ? yt4.y : (it == 2) ? yt4.z : yt4.w;
        sV += fmaxf(h - ypc, 0.f);
        const float lp = log2f(fmaxf(ypc, EPSF));
        const float lt = log2f(fmaxf(ytc, EPSF));
        const float d = lt - lp;
        sL += d * d;
    }

    if (lane == 0) { red[wave] = sV; red[4 + wave] = sL; }
    __syncthreads();
    if (tid == 0) {
        partial[blockIdx.x * 2 + 0] = red[0] + red[1] + red[2] + red[3];
        partial[blockIdx.x * 2 + 1] = red[4] + red[5] + red[6] + red[7];
    }
#undef STAGE
#undef KS
}

__global__ __launch_bounds__(256) void avl_final(
    const float* __restrict__ partial, float* __restrict__ out)
{
    const int tid  = threadIdx.x;
    const int wave = tid >> 6;
    const int lane = tid & 63;
    float s0 = 0.f, s1 = 0.f;
    for (int i = tid; i < NBLK; i += 256) {
        s0 += partial[2 * i + 0];
        s1 += partial[2 * i + 1];
    }
#pragma unroll
    for (int msk = 1; msk <= 32; msk <<= 1) {
        s0 += __shfl_xor(s0, msk, 64);
        s1 += __shfl_xor(s1, msk, 64);
    }
    __shared__ float r0[4], r1[4];
    if (lane == 0) { r0[wave] = s0; r1[wave] = s1; }
    __syncthreads();
    if (tid == 0) {
        const float vi = (r0[0] + r0[1] + r0[2] + r0[3]) * (1.0f / (float)BATCH);
        const float lm = (r1[0] + r1[1] + r1[2] + r1[3]) * (1.0f / (float)BATCH);
        out[0] = lm + 0.5f * vi;   // total_loss
        out[1] = lm;               // loss_logmse
        out[2] = vi;               // loss_violation
    }
}

extern "C" void kernel_launch(void* const* d_in, const int* in_sizes, int n_in,
                              void* d_out, int out_size, void* d_ws, size_t ws_size,
                              hipStream_t stream)
{
    const float* y_pred = (const float*)d_in[0];
    const float* y_true = (const float*)d_in[1];
    const float* P      = (const float*)d_in[2];
    const float* X      = (const float*)d_in[3];

    float* partial = (float*)d_ws;   // NBLK*2 floats = 4 KB
    avl_main<<<NBLK, 256, 0, stream>>>(y_pred, y_true, P, X, partial);
    avl_final<<<1, 256, 0, stream>>>(partial, (float*)d_out);
}